// Round 16
// baseline (199.288 us; speedup 1.0000x reference)
//
#include <hip/hip_runtime.h>
#include <hip/hip_bf16.h>
#include <cmath>

typedef __attribute__((ext_vector_type(8))) short short8;
typedef __attribute__((ext_vector_type(4))) float f32x4;

#define MFMA16(a, b, c) __builtin_amdgcn_mfma_f32_16x16x32_bf16((a), (b), (c), 0, 0, 0)

static constexpr int BB = 16, NN = 2048, DD = 256, HH = 256;

__device__ inline unsigned short f2bf(float f) {
    union { float f; unsigned int u; } v; v.f = f;
    unsigned int r = v.u + 0x7fffu + ((v.u >> 16) & 1u);
    return (unsigned short)(r >> 16);
}
__device__ inline float bf2f(unsigned short u) {
    union { unsigned int u; float f; } v; v.u = ((unsigned int)u) << 16;
    return v.f;
}
__device__ inline float gelu_exact(float x) {
    return 0.5f * x * (1.0f + erff(x * 0.7071067811865475f));
}
__device__ inline void gload_lds16(const void* g, void* l) {
    __builtin_amdgcn_global_load_lds(
        (const __attribute__((address_space(1))) unsigned int*)g,
        (__attribute__((address_space(3))) unsigned int*)l, 16, 0, 0);
}
__device__ inline void fence_mem() { asm volatile("" ::: "memory"); }
__device__ inline unsigned int cvtpk_bf16(float lo, float hi) {
    unsigned int r;
    asm("v_cvt_pk_bf16_f32 %0, %1, %2" : "=v"(r) : "v"(lo), "v"(hi));
    return r;
}

// ---- tiled weight transpose: fp32 [256][N] -> bf16 [N][256], coalesced ----
__global__ __launch_bounds__(256) void transposeT_k(const float* __restrict__ W1b,
                                                    const float* __restrict__ Wqkv,
                                                    const float* __restrict__ W2a,
                                                    unsigned short* __restrict__ W1bT,
                                                    unsigned short* __restrict__ WqkvT,
                                                    unsigned short* __restrict__ W2aT) {
    __shared__ float tl[64][65];
    int bid = blockIdx.x;  // 80 blocks: 16 W1b, 48 Wqkv, 16 W2a
    const float* src;
    unsigned short* dst;
    int N, tn, tk;
    if (bid < 16) {
        src = W1b; dst = W1bT; N = 256; tn = bid & 3; tk = bid >> 2;
    } else if (bid < 64) {
        int t2 = bid - 16;
        src = Wqkv; dst = WqkvT; N = 768; tn = t2 % 12; tk = t2 / 12;
    } else {
        int t2 = bid - 64;
        src = W2a; dst = W2aT; N = 256; tn = t2 & 3; tk = t2 >> 2;
    }
    int n0 = tn * 64, k0 = tk * 64;
    int t = threadIdx.x;
#pragma unroll
    for (int j = 0; j < 4; j++) {
        int row = (t >> 4) * 4 + j;
        f32x4 v = *(const f32x4*)(src + (size_t)(k0 + row) * N + n0 + (t & 15) * 4);
#pragma unroll
        for (int e = 0; e < 4; e++) tl[row][(t & 15) * 4 + e] = v[e];
    }
    __syncthreads();
    int n = t >> 2, cb = (t & 3) * 16;
    short8 a, b;
#pragma unroll
    for (int e = 0; e < 8; e++) {
        a[e] = (short)f2bf(tl[cb + e][n]);
        b[e] = (short)f2bf(tl[cb + 8 + e][n]);
    }
    *(short8*)(dst + (size_t)(n0 + n) * 256 + k0 + cb) = a;
    *(short8*)(dst + (size_t)(n0 + n) * 256 + k0 + cb + 8) = b;
}

// ---- fused FFN1 + qkv, 8 waves (qsub = w>>1, nhalf = w&1), acc[8] ----
__global__ __launch_bounds__(512) void ffn_qkv_k(const float* __restrict__ x,
                                                 const float* __restrict__ grd,
                                                 const float* __restrict__ W1a,
                                                 const float* __restrict__ b1a,
                                                 const unsigned short* __restrict__ W1bT,
                                                 const float* __restrict__ b1b,
                                                 const unsigned short* __restrict__ WqkvT,
                                                 unsigned short* __restrict__ qo,
                                                 unsigned short* __restrict__ ko,
                                                 unsigned short* __restrict__ vo) {
    __shared__ __attribute__((aligned(16))) char bstage[2][32768];  // 64KB weight dbuf
    __shared__ unsigned short h_lds[4][16 * 256];                   // 16KB (total 80KB)
    const int w = threadIdx.x >> 6, lane = threadIdx.x & 63;
    const int c = lane & 15, g = lane >> 4;
    const int qsub = w >> 1, nh = w & 1;
    const int rb = blockIdx.x * 64 + qsub * 16;
    const int bb = (blockIdx.x * 64) >> 11;
    const int rowinb = (rb & (NN - 1)) + c;

    const int p0r = rb + c;
    const float xv = x[p0r];
    const float gv = grd[p0r & (NN - 1)];
    short8 tf[8];
#pragma unroll
    for (int kc = 0; kc < 8; kc++) {
        int j0 = kc * 32 + g * 8;
#pragma unroll
        for (int e = 0; e < 8; e += 4) {
            f32x4 wa = *(const f32x4*)(W1a + j0 + e);
            f32x4 wb = *(const f32x4*)(W1a + 256 + j0 + e);
            f32x4 ba = *(const f32x4*)(b1a + j0 + e);
#pragma unroll
            for (int q = 0; q < 4; q++) {
                float v = xv * wa[q] + gv * wb[q] + ba[q];
                tf[kc][e + q] = (short)f2bf(gelu_exact(v));
            }
        }
    }

    const char* Bb0 = (const char*)W1bT;
    const char* Bb1 = (const char*)WqkvT;
    const char* Bb2 = (const char*)WqkvT + 256 * 512;
    const char* Bb3 = (const char*)WqkvT + 512 * 512;

#define STAGE_B(buf_, Bb_, kcp_) do {                                                    \
        _Pragma("unroll")                                                                \
        for (int i_ = 0; i_ < 4; i_++) {                                                 \
            int d_ = i_ * 8192 + w * 1024 + lane * 16;                                   \
            int row_ = d_ >> 7, sl_ = (d_ >> 4) & 7;                                     \
            gload_lds16(Bb_ + (size_t)row_ * 512 + (kcp_) * 128 +                        \
                            ((sl_ ^ (row_ & 7)) << 4),                                   \
                        &bstage[buf_][0] + d_);                                          \
        }                                                                                \
    } while (0)

    short8 hf[8];
#pragma unroll
    for (int kc = 0; kc < 8; kc++) hf[kc] = tf[kc];  // placeholder (overwritten after p0)

    STAGE_B(0, Bb0, 0);

#pragma unroll
    for (int p = 0; p < 4; p++) {
        f32x4 acc[8];
#pragma unroll
        for (int n = 0; n < 8; n++) acc[n] = (f32x4){0.f, 0.f, 0.f, 0.f};

#pragma unroll
        for (int kcp = 0; kcp < 4; kcp++) {
            const int gi = p * 4 + kcp;
            if (gi + 1 < 16) {
                const int ni = gi + 1;
                const char* nb = (ni >> 2) == 0 ? Bb0 : (ni >> 2) == 1 ? Bb1
                                : (ni >> 2) == 2 ? Bb2 : Bb3;
                STAGE_B(ni & 1, nb, ni & 3);
                asm volatile("s_waitcnt vmcnt(4)" ::: "memory");
            } else {
                asm volatile("s_waitcnt vmcnt(0)" ::: "memory");
            }
            __builtin_amdgcn_s_barrier();
            fence_mem();

            const char* bl = &bstage[gi & 1][0];
#pragma unroll
            for (int sub = 0; sub < 2; sub++) {
                short8 a = (p == 0) ? tf[kcp * 2 + sub] : hf[kcp * 2 + sub];
#pragma unroll
                for (int n = 0; n < 8; n++) {
                    int addr = (nh * 128 + n * 16 + c) * 128 +
                               ((((sub << 2) | g) ^ (c & 7)) << 4);
                    short8 bfr = *(const short8*)(bl + addr);
                    if (p == 3) acc[n] = MFMA16(bfr, a, acc[n]);  // swapped: v^T
                    else        acc[n] = MFMA16(a, bfr, acc[n]);
                }
            }
            fence_mem();
            __builtin_amdgcn_s_barrier();
            fence_mem();
        }

        if (p == 0) {
            unsigned short* hl = &h_lds[qsub][0];
#pragma unroll
            for (int n = 0; n < 8; n++) {
                int col = nh * 128 + n * 16 + c;
                float bv = b1b[col];
#pragma unroll
                for (int r = 0; r < 4; r++) {
                    int row = g * 4 + r;
                    hl[row * 256 + (col ^ ((row & 7) << 3))] = f2bf(acc[n][r] + bv);
                }
            }
            __syncthreads();
#pragma unroll
            for (int kc = 0; kc < 8; kc++) {
                hf[kc] = *(const short8*)(hl + c * 256 + ((kc * 32 + g * 8) ^ ((c & 7) << 3)));
            }
        } else if (p == 1) {
            // q scaled by (1/16) * log2(e) — softmax runs in exp2 domain
#pragma unroll
            for (int n = 0; n < 8; n++)
#pragma unroll
                for (int r = 0; r < 4; r++)
                    qo[(size_t)(rb + g * 4 + r) * 256 + nh * 128 + n * 16 + c] =
                        f2bf(acc[n][r] * (0.0625f * 1.4426950408889634f));
        } else if (p == 2) {
#pragma unroll
            for (int n = 0; n < 8; n++)
#pragma unroll
                for (int r = 0; r < 4; r++)
                    ko[(size_t)(rb + g * 4 + r) * 256 + nh * 128 + n * 16 + c] =
                        f2bf(acc[n][r]);
        } else {
#pragma unroll
            for (int m = 0; m < 8; m++) {
#pragma unroll
                for (int r = 0; r < 4; r++) {
                    int dcol = nh * 128 + m * 16 + g * 4 + r;
                    vo[((size_t)(bb * 256 + dcol)) * NN + rowinb] = f2bf(acc[m][r]);
                }
            }
        }
    }
#undef STAGE_B
}

// ---- flash attention: 8 waves (qsub=w&3, khalf=dhalf=w>>2), DECOUPLED pair softmax.
// Each khalf tracks its own running max; P halves carry their own normalization;
// consumers keep oacc_a (keys 0-31) and oacc_b (keys 32-63), rescaled via corr+flag
// published with P under B3. 3 barriers/tile. Fused FFN2a/gelu/mean epilogue.
__global__ __launch_bounds__(512) void attn_k(const unsigned short* __restrict__ qb,
                                              const unsigned short* __restrict__ kb,
                                              const unsigned short* __restrict__ vTb,
                                              const unsigned short* __restrict__ W2aT,
                                              const float* __restrict__ b2a,
                                              float* __restrict__ bar) {
    __shared__ __attribute__((aligned(16))) char smem[75392];
    char* klds = smem;                                    // 32KB swizzled K
    char* vlds = smem + 32768;                            // 32KB swizzled V^T
    unsigned int* p_lds = (unsigned int*)(smem + 65536);  // 8KB: [qsub][512 dwords]
    float* crl = (float*)(smem + 73728);                  // [qsub][khalf][16] corr
    int* flg = (int*)(smem + 74240);                      // [qsub][khalf] flags
    float* exm = (float*)(smem + 74304);                  // [8][16] (epilogue)
    float* exl = (float*)(smem + 74816);                  // [8][16]
    const int tid = threadIdx.x;
    const int w = tid >> 6, lane = tid & 63;
    const int c = lane & 15, g = lane >> 4;
    const int qsub = w & 3, dhalf = w >> 2;
    const int khalf = dhalf;
    const int bid = blockIdx.x;
    const int swz = (bid & 7) * 64 + (bid >> 3);  // bijective XCD swizzle (512%8==0)
    const int b = swz >> 5;
    const int qt = swz & 31;
    const int qbase = qt * 64 + qsub * 16;
    constexpr int NT = NN / 64;  // 32 key-tiles

    const int sl_sub = lane >> 5;
    const int sl_col = (lane & 31) * 16;
    const int vl_row = lane >> 3;
    const size_t vl_off = (size_t)vl_row * (NN * 2) + (size_t)(((lane & 7) ^ vl_row) << 4);

    const short8* qp = (const short8*)(qb + (size_t)(b * NN + qbase + c) * DD + g * 8);
    short8 qf[8];
#pragma unroll
    for (int kc = 0; kc < 8; kc++) qf[kc] = qp[kc * 4];

    const char* kb_bytes = (const char*)(kb + (size_t)(b * NN) * DD);
    const char* vb_bytes = (const char*)(vTb + (size_t)(b * DD) * NN);
    const int kswz = (c & 7) << 4;
    const int pcs = c & 7;

#define STAGE_K(kt_) do {                                                                \
        const char* gk = kb_bytes + ((size_t)((kt_) * 64 + 8 * w)) * 512;                \
        _Pragma("unroll")                                                                \
        for (int s_ = 0; s_ < 4; s_++) {                                                 \
            int row_lo = 2 * s_ + sl_sub;                                                \
            gload_lds16(gk + (size_t)row_lo * 512 + (sl_col ^ (row_lo << 4)),            \
                        klds + (8 * w + 2 * s_) * 512);                                  \
        }                                                                                \
    } while (0)
#define STAGE_V(kt_) do {                                                                \
        const char* gv = vb_bytes + (size_t)(32 * w) * (NN * 2) + (size_t)(kt_) * 128 + vl_off; \
        _Pragma("unroll")                                                                \
        for (int s_ = 0; s_ < 4; s_++) {                                                 \
            gload_lds16(gv + (size_t)(8 * s_) * (NN * 2),                                \
                        vlds + (32 * w + 8 * s_) * 128);                                 \
        }                                                                                \
    } while (0)

    f32x4 oa[8], ob2[8];  // oa: keys 0-31 P, ob2: keys 32-63 P
#pragma unroll
    for (int i = 0; i < 8; i++) {
        oa[i] = (f32x4){0.f, 0.f, 0.f, 0.f};
        ob2[i] = (f32x4){0.f, 0.f, 0.f, 0.f};
    }
    float mrun = -INFINITY;  // own-khalf running max (exp2 domain), q-row c
    float lrun = 0.f;        // own-khalf per-lane partial sum
    unsigned int* plw = p_lds + qsub * 512 + c * 32;

    STAGE_K(0);

    for (int kt = 0; kt < NT; kt++) {
        STAGE_V(kt);  // vlds free (B4 prev); flies under QK+softmax
        asm volatile("s_waitcnt vmcnt(4)" ::: "memory");  // K(kt) landed
        __builtin_amdgcn_s_barrier();  // B1: K tile published
        fence_mem();

        // ---- swapped QK^T on own 32-key half ----
        const char* klb = klds + (size_t)(khalf * 32) * 512;
        f32x4 s0 = (f32x4){0.f, 0.f, 0.f, 0.f};
        f32x4 s1 = (f32x4){0.f, 0.f, 0.f, 0.f};
        __builtin_amdgcn_s_setprio(1);
#pragma unroll
        for (int kc = 0; kc < 8; kc++) {
            short8 qv = qf[kc];
            int col = (kc * 64 + g * 16) ^ kswz;
            short8 kf0 = *(const short8*)(klb + (size_t)c * 512 + col);
            short8 kf1 = *(const short8*)(klb + (size_t)(c + 16) * 512 + col);
            s0 = MFMA16(kf0, qv, s0);
            s1 = MFMA16(kf1, qv, s1);
        }
        __builtin_amdgcn_s_setprio(0);

        // ---- own-half row max ----
        float t0 = fmaxf(fmaxf(s0[0], s0[1]), fmaxf(s0[2], s0[3]));
        float t1 = fmaxf(fmaxf(s1[0], s1[1]), fmaxf(s1[2], s1[3]));
        float tmax = fmaxf(t0, t1);
        tmax = fmaxf(tmax, __shfl_xor(tmax, 16));
        tmax = fmaxf(tmax, __shfl_xor(tmax, 32));

        bool need = tmax > mrun + 8.f;
        int fl = __any(need) ? 1 : 0;
        if (fl) {
            float mn = fmaxf(mrun, tmax);
            float corr = exp2f(mrun - mn);
#pragma unroll
            for (int r = 0; r < 4; r++) s0[r] = exp2f(s0[r] - mn);
#pragma unroll
            for (int r = 0; r < 4; r++) s1[r] = exp2f(s1[r] - mn);
            lrun = lrun * corr + ((s0[0] + s0[1]) + (s0[2] + s0[3])) +
                   ((s1[0] + s1[1]) + (s1[2] + s1[3]));
            mrun = mn;
            if (g == 0) crl[(qsub * 2 + khalf) * 16 + c] = corr;  // publish rescale
        } else {
#pragma unroll
            for (int r = 0; r < 4; r++) s0[r] = exp2f(s0[r] - mrun);
#pragma unroll
            for (int r = 0; r < 4; r++) s1[r] = exp2f(s1[r] - mrun);
            lrun += ((s0[0] + s0[1]) + (s0[2] + s0[3])) +
                    ((s1[0] + s1[1]) + (s1[2] + s1[3]));
        }
        if (lane == 0) flg[qsub * 2 + khalf] = fl;

        // ---- pack own-half P via cvt_pk, chunk-swizzled ----
        {
            int jb0 = khalf * 16 + 2 * g;
            int jb1 = khalf * 16 + 8 + 2 * g;
#pragma unroll
            for (int h = 0; h < 2; h++) {
                int j = jb0 + h;
                plw[(((j >> 2) ^ pcs) << 2) | (j & 3)] = cvtpk_bf16(s0[2 * h], s0[2 * h + 1]);
                j = jb1 + h;
                plw[(((j >> 2) ^ pcs) << 2) | (j & 3)] = cvtpk_bf16(s1[2 * h], s1[2 * h + 1]);
            }
        }
        fence_mem();
        asm volatile("s_waitcnt vmcnt(0)" ::: "memory");  // V(kt) landed
        __builtin_amdgcn_s_barrier();  // B3: P + corr/flag + V published
        fence_mem();

        // ---- prefetch K(kt+1): all QK reads provably done (every wave passed B3) ----
        if (kt + 1 < NT) STAGE_K(kt + 1);

        // ---- conditional rescale from published corr ----
        int f0 = flg[qsub * 2 + 0];
        int f1 = flg[qsub * 2 + 1];
        if (f0) {
            f32x4 ca = *(const f32x4*)(crl + (qsub * 2 + 0) * 16 + 4 * g);
#pragma unroll
            for (int nc = 0; nc < 8; nc++)
#pragma unroll
                for (int r = 0; r < 4; r++) oa[nc][r] *= ca[r];
        }
        if (f1) {
            f32x4 cb = *(const f32x4*)(crl + (qsub * 2 + 1) * 16 + 4 * g);
#pragma unroll
            for (int nc = 0; nc < 8; nc++)
#pragma unroll
                for (int r = 0; r < 4; r++) ob2[nc][r] *= cb[r];
        }

        short8 pf0 = *(const short8*)(plw + ((g ^ pcs) << 2));
        short8 pf1 = *(const short8*)(plw + (((4 + g) ^ pcs) << 2));
        __builtin_amdgcn_s_setprio(1);
#pragma unroll
        for (int nc = 0; nc < 8; nc++) {
            const char* vr = vlds + (size_t)(dhalf * 128 + nc * 16 + c) * 128;
            short8 vf0 = *(const short8*)(vr + ((g ^ pcs) << 4));
            short8 vf1 = *(const short8*)(vr + (((4 + g) ^ pcs) << 4));
            oa[nc] = MFMA16(pf0, vf0, oa[nc]);
            ob2[nc] = MFMA16(pf1, vf1, ob2[nc]);
        }
        __builtin_amdgcn_s_setprio(0);

        fence_mem();
        __builtin_amdgcn_s_barrier();  // B4: tile fully consumed (guards re-stage)
        fence_mem();
    }
#undef STAGE_K
#undef STAGE_V

    // ---- epilogue: exchange (m,l) across khalf pair, exact merge ----
    float lt = lrun;
    lt += __shfl_xor(lt, 16);
    lt += __shfl_xor(lt, 32);  // own-half total for q=c
    if (g == 0) { exm[w * 16 + c] = mrun; exl[w * 16 + c] = lt; }
    fence_mem();
    __builtin_amdgcn_s_barrier();
    fence_mem();
    float m_oth = exm[(w ^ 4) * 16 + c];
    float l_oth = exl[(w ^ 4) * 16 + c];
    float m0 = (khalf == 0) ? mrun : m_oth;
    float l0 = (khalf == 0) ? lt : l_oth;
    float m1 = (khalf == 0) ? m_oth : mrun;
    float l1 = (khalf == 0) ? l_oth : lt;
    float M = fmaxf(m0, m1);
    float sa = exp2f(m0 - M);
    float sb = exp2f(m1 - M);
    float inv = 1.f / (l0 * sa + l1 * sb);
    float sar[4], sbr[4], inv_r[4];
#pragma unroll
    for (int r = 0; r < 4; r++) {
        sar[r] = __shfl(sa, 20 * g + r);
        sbr[r] = __shfl(sb, 20 * g + r);
        inv_r[r] = __shfl(inv, 20 * g + r);
    }

    // ---- write normalized o-tile into reused LDS ----
    unsigned short* ol = (unsigned short*)smem;
#pragma unroll
    for (int r = 0; r < 4; r++) {
        int row = 4 * g + r;
        int swr = (row & 7) << 3;
#pragma unroll
        for (int nc = 0; nc < 8; nc++) {
            int col = dhalf * 128 + nc * 16 + c;
            float ov = (oa[nc][r] * sar[r] + ob2[nc][r] * sbr[r]) * inv_r[r];
            ol[qsub * 4096 + row * 256 + (col ^ swr)] = f2bf(ov);
        }
    }
    fence_mem();
    __builtin_amdgcn_s_barrier();  // o-tile complete
    fence_mem();

    // ---- fused FFN2a + gelu + mean: wave w owns output cols [32w, 32w+32) ----
    {
        const int wcol = w * 32;
        float colsum[2] = {0.f, 0.f};
#pragma unroll
        for (int q2 = 0; q2 < 4; q2++) {
            f32x4 acc2[2];
            acc2[0] = (f32x4){0.f, 0.f, 0.f, 0.f};
            acc2[1] = (f32x4){0.f, 0.f, 0.f, 0.f};
            const unsigned short* oq = ol + q2 * 4096;
            const int swc = (c & 7) << 3;
#pragma unroll
            for (int kc = 0; kc < 8; kc++) {
                short8 a = *(const short8*)(oq + c * 256 + ((kc * 32 + g * 8) ^ swc));
#pragma unroll
                for (int nc = 0; nc < 2; nc++) {
                    short8 bfr = *(const short8*)(W2aT + (size_t)(wcol + nc * 16 + c) * 256 + kc * 32 + g * 8);
                    acc2[nc] = MFMA16(a, bfr, acc2[nc]);
                }
            }
#pragma unroll
            for (int nc = 0; nc < 2; nc++) {
                float bv = b2a[wcol + nc * 16 + c];
                float s2 = 0.f;
#pragma unroll
                for (int r = 0; r < 4; r++) s2 += gelu_exact(acc2[nc][r] + bv);
                colsum[nc] += s2;
            }
        }
#pragma unroll
        for (int nc = 0; nc < 2; nc++) {
            float s2 = colsum[nc];
            s2 += __shfl_xor(s2, 16);
            s2 += __shfl_xor(s2, 32);
            if (g == 0) atomicAdd(&bar[b * 256 + wcol + nc * 16 + c], s2);
        }
    }
}

// ---- final projection ----
__global__ void final_k(const float* __restrict__ bar, const float* __restrict__ W2b,
                        const float* __restrict__ b2b, float* __restrict__ out) {
    int b = blockIdx.x, d = threadIdx.x;
    float s = 0.f;
    for (int h = 0; h < HH; h++) s += bar[b * HH + h] * W2b[h * DD + d];
    out[b * DD + d] = b2b[d] + s * (1.f / (float)NN);
}

extern "C" void kernel_launch(void* const* d_in, const int* in_sizes, int n_in,
                              void* d_out, int out_size, void* d_ws, size_t ws_size,
                              hipStream_t stream) {
    (void)in_sizes; (void)n_in; (void)out_size; (void)ws_size;
    const float* x    = (const float*)d_in[0];
    const float* grd  = (const float*)d_in[1];
    const float* W1a  = (const float*)d_in[2];
    const float* b1a  = (const float*)d_in[3];
    const float* W1b  = (const float*)d_in[4];
    const float* b1b  = (const float*)d_in[5];
    const float* Wqkv = (const float*)d_in[6];
    const float* W2a  = (const float*)d_in[7];
    const float* b2a  = (const float*)d_in[8];
    const float* W2b  = (const float*)d_in[9];
    const float* b2b  = (const float*)d_in[10];
    float* out = (float*)d_out;

    char* ws = (char*)d_ws;
    const size_t MB = 1024 * 1024;
    unsigned short* q_buf  = (unsigned short*)(ws + 0);
    unsigned short* k_buf  = (unsigned short*)(ws + 16 * MB);
    unsigned short* vT_buf = (unsigned short*)(ws + 32 * MB);
    unsigned short* W1bT   = (unsigned short*)(ws + 80 * MB);
    unsigned short* WqkvT  = (unsigned short*)(ws + 80 * MB + 512 * 1024);
    unsigned short* W2aT   = (unsigned short*)(ws + 81 * MB);
    float*          bar    = (float*)(ws + 81 * MB + 256 * 1024);

    transposeT_k<<<dim3(80), 256, 0, stream>>>(W1b, Wqkv, W2a, W1bT, WqkvT, W2aT);
    ffn_qkv_k<<<dim3(512), 512, 0, stream>>>(x, grd, W1a, b1a, W1bT, b1b, WqkvT,
                                             q_buf, k_buf, vT_buf);
    hipMemsetAsync(bar, 0, BB * HH * sizeof(float), stream);
    attn_k<<<dim3(512), 512, 0, stream>>>(q_buf, k_buf, vT_buf, W2aT, b2a, bar);
    final_k<<<dim3(BB), 256, 0, stream>>>(bar, W2b, b2b, out);
}

// Round 17
// 196.014 us; speedup vs baseline: 1.0167x; 1.0167x over previous
//
#include <hip/hip_runtime.h>
#include <hip/hip_bf16.h>
#include <cmath>

typedef __attribute__((ext_vector_type(8))) short short8;
typedef __attribute__((ext_vector_type(4))) float f32x4;

#define MFMA16(a, b, c) __builtin_amdgcn_mfma_f32_16x16x32_bf16((a), (b), (c), 0, 0, 0)

static constexpr int BB = 16, NN = 2048, DD = 256, HH = 256;

__device__ inline unsigned short f2bf(float f) {
    union { float f; unsigned int u; } v; v.f = f;
    unsigned int r = v.u + 0x7fffu + ((v.u >> 16) & 1u);
    return (unsigned short)(r >> 16);
}
__device__ inline float bf2f(unsigned short u) {
    union { unsigned int u; float f; } v; v.u = ((unsigned int)u) << 16;
    return v.f;
}
__device__ inline float gelu_exact(float x) {
    return 0.5f * x * (1.0f + erff(x * 0.7071067811865475f));
}
__device__ inline void gload_lds16(const void* g, void* l) {
    __builtin_amdgcn_global_load_lds(
        (const __attribute__((address_space(1))) unsigned int*)g,
        (__attribute__((address_space(3))) unsigned int*)l, 16, 0, 0);
}
__device__ inline void fence_mem() { asm volatile("" ::: "memory"); }
__device__ inline unsigned int cvtpk_bf16(float lo, float hi) {
    unsigned int r;
    asm("v_cvt_pk_bf16_f32 %0, %1, %2" : "=v"(r) : "v"(lo), "v"(hi));
    return r;
}

// ---- tiled weight transpose: fp32 [256][N] -> bf16 [N][256], coalesced ----
// Block 0 additionally zeroes bar[16][256] (replaces hipMemsetAsync dispatch).
__global__ __launch_bounds__(256) void transposeT_k(const float* __restrict__ W1b,
                                                    const float* __restrict__ Wqkv,
                                                    const float* __restrict__ W2a,
                                                    unsigned short* __restrict__ W1bT,
                                                    unsigned short* __restrict__ WqkvT,
                                                    unsigned short* __restrict__ W2aT,
                                                    float* __restrict__ bar) {
    __shared__ float tl[64][65];
    int bid = blockIdx.x;  // 80 blocks: 16 W1b, 48 Wqkv, 16 W2a
    int t = threadIdx.x;
    if (bid == 0) {
        f32x4 z = (f32x4){0.f, 0.f, 0.f, 0.f};
#pragma unroll
        for (int i = 0; i < 4; i++) *(f32x4*)(bar + t * 16 + i * 4) = z;
    }
    const float* src;
    unsigned short* dst;
    int N, tn, tk;
    if (bid < 16) {
        src = W1b; dst = W1bT; N = 256; tn = bid & 3; tk = bid >> 2;
    } else if (bid < 64) {
        int t2 = bid - 16;
        src = Wqkv; dst = WqkvT; N = 768; tn = t2 % 12; tk = t2 / 12;
    } else {
        int t2 = bid - 64;
        src = W2a; dst = W2aT; N = 256; tn = t2 & 3; tk = t2 >> 2;
    }
    int n0 = tn * 64, k0 = tk * 64;
#pragma unroll
    for (int j = 0; j < 4; j++) {
        int row = (t >> 4) * 4 + j;
        f32x4 v = *(const f32x4*)(src + (size_t)(k0 + row) * N + n0 + (t & 15) * 4);
#pragma unroll
        for (int e = 0; e < 4; e++) tl[row][(t & 15) * 4 + e] = v[e];
    }
    __syncthreads();
    int n = t >> 2, cb = (t & 3) * 16;
    short8 a, b;
#pragma unroll
    for (int e = 0; e < 8; e++) {
        a[e] = (short)f2bf(tl[cb + e][n]);
        b[e] = (short)f2bf(tl[cb + 8 + e][n]);
    }
    *(short8*)(dst + (size_t)(n0 + n) * 256 + k0 + cb) = a;
    *(short8*)(dst + (size_t)(n0 + n) * 256 + k0 + cb + 8) = b;
}

// ---- fused FFN1 + qkv, 8 waves (qsub = w>>1, nhalf = w&1), acc[8] ----
__global__ __launch_bounds__(512) void ffn_qkv_k(const float* __restrict__ x,
                                                 const float* __restrict__ grd,
                                                 const float* __restrict__ W1a,
                                                 const float* __restrict__ b1a,
                                                 const unsigned short* __restrict__ W1bT,
                                                 const float* __restrict__ b1b,
                                                 const unsigned short* __restrict__ WqkvT,
                                                 unsigned short* __restrict__ qo,
                                                 unsigned short* __restrict__ ko,
                                                 unsigned short* __restrict__ vo) {
    __shared__ __attribute__((aligned(16))) char bstage[2][32768];  // 64KB weight dbuf
    __shared__ unsigned short h_lds[4][16 * 256];                   // 16KB (total 80KB)
    const int w = threadIdx.x >> 6, lane = threadIdx.x & 63;
    const int c = lane & 15, g = lane >> 4;
    const int qsub = w >> 1, nh = w & 1;
    const int rb = blockIdx.x * 64 + qsub * 16;
    const int bb = (blockIdx.x * 64) >> 11;
    const int rowinb = (rb & (NN - 1)) + c;

    const int p0r = rb + c;
    const float xv = x[p0r];
    const float gv = grd[p0r & (NN - 1)];
    short8 tf[8];
#pragma unroll
    for (int kc = 0; kc < 8; kc++) {
        int j0 = kc * 32 + g * 8;
#pragma unroll
        for (int e = 0; e < 8; e += 4) {
            f32x4 wa = *(const f32x4*)(W1a + j0 + e);
            f32x4 wb = *(const f32x4*)(W1a + 256 + j0 + e);
            f32x4 ba = *(const f32x4*)(b1a + j0 + e);
#pragma unroll
            for (int q = 0; q < 4; q++) {
                float v = xv * wa[q] + gv * wb[q] + ba[q];
                tf[kc][e + q] = (short)f2bf(gelu_exact(v));
            }
        }
    }

    const char* Bb0 = (const char*)W1bT;
    const char* Bb1 = (const char*)WqkvT;
    const char* Bb2 = (const char*)WqkvT + 256 * 512;
    const char* Bb3 = (const char*)WqkvT + 512 * 512;

#define STAGE_B(buf_, Bb_, kcp_) do {                                                    \
        _Pragma("unroll")                                                                \
        for (int i_ = 0; i_ < 4; i_++) {                                                 \
            int d_ = i_ * 8192 + w * 1024 + lane * 16;                                   \
            int row_ = d_ >> 7, sl_ = (d_ >> 4) & 7;                                     \
            gload_lds16(Bb_ + (size_t)row_ * 512 + (kcp_) * 128 +                        \
                            ((sl_ ^ (row_ & 7)) << 4),                                   \
                        &bstage[buf_][0] + d_);                                          \
        }                                                                                \
    } while (0)

    short8 hf[8];
#pragma unroll
    for (int kc = 0; kc < 8; kc++) hf[kc] = tf[kc];  // placeholder (overwritten after p0)

    STAGE_B(0, Bb0, 0);

#pragma unroll
    for (int p = 0; p < 4; p++) {
        f32x4 acc[8];
#pragma unroll
        for (int n = 0; n < 8; n++) acc[n] = (f32x4){0.f, 0.f, 0.f, 0.f};

#pragma unroll
        for (int kcp = 0; kcp < 4; kcp++) {
            const int gi = p * 4 + kcp;
            if (gi + 1 < 16) {
                const int ni = gi + 1;
                const char* nb = (ni >> 2) == 0 ? Bb0 : (ni >> 2) == 1 ? Bb1
                                : (ni >> 2) == 2 ? Bb2 : Bb3;
                STAGE_B(ni & 1, nb, ni & 3);
                asm volatile("s_waitcnt vmcnt(4)" ::: "memory");
            } else {
                asm volatile("s_waitcnt vmcnt(0)" ::: "memory");
            }
            __builtin_amdgcn_s_barrier();
            fence_mem();

            const char* bl = &bstage[gi & 1][0];
#pragma unroll
            for (int sub = 0; sub < 2; sub++) {
                short8 a = (p == 0) ? tf[kcp * 2 + sub] : hf[kcp * 2 + sub];
#pragma unroll
                for (int n = 0; n < 8; n++) {
                    int addr = (nh * 128 + n * 16 + c) * 128 +
                               ((((sub << 2) | g) ^ (c & 7)) << 4);
                    short8 bfr = *(const short8*)(bl + addr);
                    if (p == 3) acc[n] = MFMA16(bfr, a, acc[n]);  // swapped: v^T
                    else        acc[n] = MFMA16(a, bfr, acc[n]);
                }
            }
            fence_mem();
            __builtin_amdgcn_s_barrier();
            fence_mem();
        }

        if (p == 0) {
            unsigned short* hl = &h_lds[qsub][0];
#pragma unroll
            for (int n = 0; n < 8; n++) {
                int col = nh * 128 + n * 16 + c;
                float bv = b1b[col];
#pragma unroll
                for (int r = 0; r < 4; r++) {
                    int row = g * 4 + r;
                    hl[row * 256 + (col ^ ((row & 7) << 3))] = f2bf(acc[n][r] + bv);
                }
            }
            __syncthreads();
#pragma unroll
            for (int kc = 0; kc < 8; kc++) {
                hf[kc] = *(const short8*)(hl + c * 256 + ((kc * 32 + g * 8) ^ ((c & 7) << 3)));
            }
        } else if (p == 1) {
            // q scaled by (1/16) * log2(e) — softmax runs in exp2 domain
#pragma unroll
            for (int n = 0; n < 8; n++)
#pragma unroll
                for (int r = 0; r < 4; r++)
                    qo[(size_t)(rb + g * 4 + r) * 256 + nh * 128 + n * 16 + c] =
                        f2bf(acc[n][r] * (0.0625f * 1.4426950408889634f));
        } else if (p == 2) {
#pragma unroll
            for (int n = 0; n < 8; n++)
#pragma unroll
                for (int r = 0; r < 4; r++)
                    ko[(size_t)(rb + g * 4 + r) * 256 + nh * 128 + n * 16 + c] =
                        f2bf(acc[n][r]);
        } else {
#pragma unroll
            for (int m = 0; m < 8; m++) {
#pragma unroll
                for (int r = 0; r < 4; r++) {
                    int dcol = nh * 128 + m * 16 + g * 4 + r;
                    vo[((size_t)(bb * 256 + dcol)) * NN + rowinb] = f2bf(acc[m][r]);
                }
            }
        }
    }
#undef STAGE_B
}

// ---- flash attention (R15-best): 8 waves (qsub=w&3, khalf=dhalf=w>>2), pair-split S,
// pipelined K/V staging, exp2 softmax, cvt_pk packing, fused FFN2a/gelu/mean epilogue.
__global__ __launch_bounds__(512) void attn_k(const unsigned short* __restrict__ qb,
                                              const unsigned short* __restrict__ kb,
                                              const unsigned short* __restrict__ vTb,
                                              const unsigned short* __restrict__ W2aT,
                                              const float* __restrict__ b2a,
                                              float* __restrict__ bar) {
    __shared__ __attribute__((aligned(16))) char smem[74752];
    char* klds = smem;                                    // 32KB swizzled K
    char* vlds = smem + 32768;                            // 32KB swizzled V^T
    unsigned int* p_lds = (unsigned int*)(smem + 65536);  // 8KB: [qsub][512 dwords]
    float* exm = (float*)(smem + 65536 + 8192);           // [8][16]
    float* exl = exm + 128;                               // [8][16]
    const int tid = threadIdx.x;
    const int w = tid >> 6, lane = tid & 63;
    const int c = lane & 15, g = lane >> 4;
    const int qsub = w & 3, dhalf = w >> 2;
    const int khalf = dhalf;
    const int bid = blockIdx.x;
    const int swz = (bid & 7) * 64 + (bid >> 3);  // bijective XCD swizzle (512%8==0)
    const int b = swz >> 5;
    const int qt = swz & 31;
    const int qbase = qt * 64 + qsub * 16;
    constexpr int NT = NN / 64;  // 32 key-tiles

    const int sl_sub = lane >> 5;
    const int sl_col = (lane & 31) * 16;
    const int vl_row = lane >> 3;
    const size_t vl_off = (size_t)vl_row * (NN * 2) + (size_t)(((lane & 7) ^ vl_row) << 4);

    const short8* qp = (const short8*)(qb + (size_t)(b * NN + qbase + c) * DD + g * 8);
    short8 qf[8];
#pragma unroll
    for (int kc = 0; kc < 8; kc++) qf[kc] = qp[kc * 4];

    const char* kb_bytes = (const char*)(kb + (size_t)(b * NN) * DD);
    const char* vb_bytes = (const char*)(vTb + (size_t)(b * DD) * NN);
    const int kswz = (c & 7) << 4;
    const int pcs = c & 7;

#define STAGE_K(kt_) do {                                                                \
        const char* gk = kb_bytes + ((size_t)((kt_) * 64 + 8 * w)) * 512;                \
        _Pragma("unroll")                                                                \
        for (int s_ = 0; s_ < 4; s_++) {                                                 \
            int row_lo = 2 * s_ + sl_sub;                                                \
            gload_lds16(gk + (size_t)row_lo * 512 + (sl_col ^ (row_lo << 4)),            \
                        klds + (8 * w + 2 * s_) * 512);                                  \
        }                                                                                \
    } while (0)
#define STAGE_V(kt_) do {                                                                \
        const char* gv = vb_bytes + (size_t)(32 * w) * (NN * 2) + (size_t)(kt_) * 128 + vl_off; \
        _Pragma("unroll")                                                                \
        for (int s_ = 0; s_ < 4; s_++) {                                                 \
            gload_lds16(gv + (size_t)(8 * s_) * (NN * 2),                                \
                        vlds + (32 * w + 8 * s_) * 128);                                 \
        }                                                                                \
    } while (0)

    f32x4 oacc[8];
#pragma unroll
    for (int i = 0; i < 8; i++) oacc[i] = (f32x4){0.f, 0.f, 0.f, 0.f};
    float mrun = -INFINITY;  // running max (exp2 domain) for q-row c
    float lrun = 0.f;        // per-lane partial sum (this lane's 8 keys of own half)
    unsigned int* plw = p_lds + qsub * 512 + c * 32;

    STAGE_K(0);  // prologue: K(0) in flight

    for (int kt = 0; kt < NT; kt++) {
        STAGE_V(kt);  // vlds free (B4 of prev iter); flies under QK+softmax
        asm volatile("s_waitcnt vmcnt(4)" ::: "memory");  // K(kt) ready, V(kt) in flight
        __builtin_amdgcn_s_barrier();  // B1: K tile published
        fence_mem();

        // ---- swapped QK^T on own 32-key half ----
        const char* klb = klds + (size_t)(khalf * 32) * 512;
        f32x4 s0 = (f32x4){0.f, 0.f, 0.f, 0.f};
        f32x4 s1 = (f32x4){0.f, 0.f, 0.f, 0.f};
        __builtin_amdgcn_s_setprio(1);
#pragma unroll
        for (int kc = 0; kc < 8; kc++) {
            short8 qv = qf[kc];
            int col = (kc * 64 + g * 16) ^ kswz;
            short8 kf0 = *(const short8*)(klb + (size_t)c * 512 + col);
            short8 kf1 = *(const short8*)(klb + (size_t)(c + 16) * 512 + col);
            s0 = MFMA16(kf0, qv, s0);
            s1 = MFMA16(kf1, qv, s1);
        }
        __builtin_amdgcn_s_setprio(0);

        float t0 = fmaxf(fmaxf(s0[0], s0[1]), fmaxf(s0[2], s0[3]));
        float t1 = fmaxf(fmaxf(s1[0], s1[1]), fmaxf(s1[2], s1[3]));
        float tmo = fmaxf(t0, t1);
        tmo = fmaxf(tmo, __shfl_xor(tmo, 16));
        tmo = fmaxf(tmo, __shfl_xor(tmo, 32));
        if (g == 0) exm[w * 16 + c] = tmo;
        fence_mem();
        __builtin_amdgcn_s_barrier();  // B2: partner max visible; QK reads all done
        fence_mem();
        float tmax = fmaxf(tmo, exm[(w ^ 4) * 16 + c]);

        // klds free for next tile (all QK reads done before B2) — prefetch K(kt+1)
        if (kt + 1 < NT) STAGE_K(kt + 1);

        bool need = tmax > mrun + 8.f;
        if (__any(need)) {
            float mn = fmaxf(mrun, tmax);
            float corr = exp2f(mrun - mn);
#pragma unroll
            for (int r = 0; r < 4; r++) s0[r] = exp2f(s0[r] - mn);
#pragma unroll
            for (int r = 0; r < 4; r++) s1[r] = exp2f(s1[r] - mn);
            lrun = lrun * corr + ((s0[0] + s0[1]) + (s0[2] + s0[3])) +
                   ((s1[0] + s1[1]) + (s1[2] + s1[3]));
            mrun = mn;
#pragma unroll
            for (int r = 0; r < 4; r++) {
                float cr = __shfl(corr, 20 * g + r);
#pragma unroll
                for (int nc = 0; nc < 8; nc++) oacc[nc][r] *= cr;
            }
        } else {
#pragma unroll
            for (int r = 0; r < 4; r++) s0[r] = exp2f(s0[r] - mrun);
#pragma unroll
            for (int r = 0; r < 4; r++) s1[r] = exp2f(s1[r] - mrun);
            lrun += ((s0[0] + s0[1]) + (s0[2] + s0[3])) +
                    ((s1[0] + s1[1]) + (s1[2] + s1[3]));
        }

        // ---- pack own-half P via v_cvt_pk_bf16_f32, chunk-swizzled ----
        {
            int jb0 = khalf * 16 + 2 * g;
            int jb1 = khalf * 16 + 8 + 2 * g;
#pragma unroll
            for (int h = 0; h < 2; h++) {
                int j = jb0 + h;
                plw[(((j >> 2) ^ pcs) << 2) | (j & 3)] = cvtpk_bf16(s0[2 * h], s0[2 * h + 1]);
                j = jb1 + h;
                plw[(((j >> 2) ^ pcs) << 2) | (j & 3)] = cvtpk_bf16(s1[2 * h], s1[2 * h + 1]);
            }
        }
        fence_mem();
        if (kt + 1 < NT) {
            asm volatile("s_waitcnt vmcnt(4)" ::: "memory");  // V(kt) ready, K(kt+1) in flight
        } else {
            asm volatile("s_waitcnt vmcnt(0)" ::: "memory");
        }
        __builtin_amdgcn_s_barrier();  // B3: P halves + V tile published
        fence_mem();

        short8 pf0 = *(const short8*)(plw + ((g ^ pcs) << 2));
        short8 pf1 = *(const short8*)(plw + (((4 + g) ^ pcs) << 2));
        __builtin_amdgcn_s_setprio(1);
#pragma unroll
        for (int nc = 0; nc < 8; nc++) {
            const char* vr = vlds + (size_t)(dhalf * 128 + nc * 16 + c) * 128;
            short8 vf0 = *(const short8*)(vr + ((g ^ pcs) << 4));
            short8 vf1 = *(const short8*)(vr + (((4 + g) ^ pcs) << 4));
            oacc[nc] = MFMA16(pf0, vf0, oacc[nc]);
            oacc[nc] = MFMA16(pf1, vf1, oacc[nc]);
        }
        __builtin_amdgcn_s_setprio(0);

        fence_mem();
        __builtin_amdgcn_s_barrier();  // B4: tile fully consumed (guards vlds re-stage)
        fence_mem();
    }
#undef STAGE_K
#undef STAGE_V

    // ---- combine l across pair ----
    float lt = lrun;
    lt += __shfl_xor(lt, 16);
    lt += __shfl_xor(lt, 32);
    if (g == 0) exl[w * 16 + c] = lt;
    fence_mem();
    __builtin_amdgcn_s_barrier();
    fence_mem();
    lt += exl[(w ^ 4) * 16 + c];
    float inv_r[4];
#pragma unroll
    for (int r = 0; r < 4; r++) inv_r[r] = 1.f / __shfl(lt, 20 * g + r);

    // ---- write normalized o-tile into reused LDS ----
    unsigned short* ol = (unsigned short*)smem;
#pragma unroll
    for (int r = 0; r < 4; r++) {
        int row = 4 * g + r;
        int swr = (row & 7) << 3;
#pragma unroll
        for (int nc = 0; nc < 8; nc++) {
            int col = dhalf * 128 + nc * 16 + c;
            ol[qsub * 4096 + row * 256 + (col ^ swr)] = f2bf(oacc[nc][r] * inv_r[r]);
        }
    }
    fence_mem();
    __builtin_amdgcn_s_barrier();  // o-tile complete
    fence_mem();

    // ---- fused FFN2a + gelu + mean: wave w owns output cols [32w, 32w+32) ----
    {
        const int wcol = w * 32;
        float colsum[2] = {0.f, 0.f};
#pragma unroll
        for (int q2 = 0; q2 < 4; q2++) {
            f32x4 acc2[2];
            acc2[0] = (f32x4){0.f, 0.f, 0.f, 0.f};
            acc2[1] = (f32x4){0.f, 0.f, 0.f, 0.f};
            const unsigned short* oq = ol + q2 * 4096;
            const int swc = (c & 7) << 3;
#pragma unroll
            for (int kc = 0; kc < 8; kc++) {
                short8 a = *(const short8*)(oq + c * 256 + ((kc * 32 + g * 8) ^ swc));
#pragma unroll
                for (int nc = 0; nc < 2; nc++) {
                    short8 bfr = *(const short8*)(W2aT + (size_t)(wcol + nc * 16 + c) * 256 + kc * 32 + g * 8);
                    acc2[nc] = MFMA16(a, bfr, acc2[nc]);
                }
            }
#pragma unroll
            for (int nc = 0; nc < 2; nc++) {
                float bv = b2a[wcol + nc * 16 + c];
                float s2 = 0.f;
#pragma unroll
                for (int r = 0; r < 4; r++) s2 += gelu_exact(acc2[nc][r] + bv);
                colsum[nc] += s2;
            }
        }
#pragma unroll
        for (int nc = 0; nc < 2; nc++) {
            float s2 = colsum[nc];
            s2 += __shfl_xor(s2, 16);
            s2 += __shfl_xor(s2, 32);
            if (g == 0) atomicAdd(&bar[b * 256 + wcol + nc * 16 + c], s2);
        }
    }
}

// ---- final projection ----
__global__ void final_k(const float* __restrict__ bar, const float* __restrict__ W2b,
                        const float* __restrict__ b2b, float* __restrict__ out) {
    int b = blockIdx.x, d = threadIdx.x;
    float s = 0.f;
    for (int h = 0; h < HH; h++) s += bar[b * HH + h] * W2b[h * DD + d];
    out[b * DD + d] = b2b[d] + s * (1.f / (float)NN);
}

extern "C" void kernel_launch(void* const* d_in, const int* in_sizes, int n_in,
                              void* d_out, int out_size, void* d_ws, size_t ws_size,
                              hipStream_t stream) {
    (void)in_sizes; (void)n_in; (void)out_size; (void)ws_size;
    const float* x    = (const float*)d_in[0];
    const float* grd  = (const float*)d_in[1];
    const float* W1a  = (const float*)d_in[2];
    const float* b1a  = (const float*)d_in[3];
    const float* W1b  = (const float*)d_in[4];
    const float* b1b  = (const float*)d_in[5];
    const float* Wqkv = (const float*)d_in[6];
    const float* W2a  = (const float*)d_in[7];
    const float* b2a  = (const float*)d_in[8];
    const float* W2b  = (const float*)d_in[9];
    const float* b2b  = (const float*)d_in[10];
    float* out = (float*)d_out;

    char* ws = (char*)d_ws;
    const size_t MB = 1024 * 1024;
    unsigned short* q_buf  = (unsigned short*)(ws + 0);
    unsigned short* k_buf  = (unsigned short*)(ws + 16 * MB);
    unsigned short* vT_buf = (unsigned short*)(ws + 32 * MB);
    unsigned short* W1bT   = (unsigned short*)(ws + 80 * MB);
    unsigned short* WqkvT  = (unsigned short*)(ws + 80 * MB + 512 * 1024);
    unsigned short* W2aT   = (unsigned short*)(ws + 81 * MB);
    float*          bar    = (float*)(ws + 81 * MB + 256 * 1024);

    transposeT_k<<<dim3(80), 256, 0, stream>>>(W1b, Wqkv, W2a, W1bT, WqkvT, W2aT, bar);
    ffn_qkv_k<<<dim3(512), 512, 0, stream>>>(x, grd, W1a, b1a, W1bT, b1b, WqkvT,
                                             q_buf, k_buf, vT_buf);
    attn_k<<<dim3(512), 512, 0, stream>>>(q_buf, k_buf, vT_buf, W2aT, b2a, bar);
    final_k<<<dim3(BB), 256, 0, stream>>>(bar, W2b, b2b, out);
}